// Round 5
// baseline (494.589 us; speedup 1.0000x reference)
//
#include <hip/hip_runtime.h>

typedef unsigned short u16;
typedef __bf16 bf16x8 __attribute__((ext_vector_type(8)));
typedef float f32x4 __attribute__((ext_vector_type(4)));

#define Bsz 8192
#define BIGI (1 << 30)

// ws element offsets (u16 elements)
#define OFF_FEAT   0
#define OFF_WCOMB  8388608    // [W_al (512x1024) | W_ol (1536x1024)]
#define OFF_WQ     10485760   // 512x512 (W_in rows 0..511)
#define OFF_WOUT   10747904   // 512x512
#define OFF_WAH    11010048   // 512x1024
#define OFF_PACK   11534336   // 3 x 1536x512 : [Wk; Wv; W_oh[z]]
#define OFF_LAT    13893632   // B x 2048 : [agent | opp0 | opp1 | opp2]
#define OFF_Q      30670848   // B x 512 (later reused for agent_head)
#define OFF_KV     34865152   // 3 x B x 1024 : [k | v]
#define OFF_ATT    60030976   // B x 512
#define OFF_AO     64225280   // B x 512
#define OFF_OPH    68419584   // 3 x B x 512

// d_out offsets (fp32 elements)
#define OUT_AP 0
#define OUT_AV 49152
#define OUT_OP 57344
#define OUT_OV 204800
#define OUT_IN 229376

__device__ __forceinline__ u16 f2bf(float f) {
  return __builtin_bit_cast(u16, (__bf16)f);
}
__device__ __forceinline__ float bf2f(u16 u) {
  return (float)__builtin_bit_cast(__bf16, u);
}

// ---------- fp32 -> bf16 conversion + B-pack build ----------
// segments (float4 units): feat, W_al, W_ol, Wq(=W_in rows 0..511), W_out,
// W_ah, pack(3x1536x512 from W_in rows 512..1535 + W_oh[z])
#define CV_E0 2097152
#define CV_E1 2228224
#define CV_E2 2621440
#define CV_E3 2686976
#define CV_E4 2752512
#define CV_E5 2883584
#define CV_E6 3473408
__global__ __launch_bounds__(256) void convert_all(
    const float* __restrict__ f, const float* __restrict__ wal,
    const float* __restrict__ wol, const float* __restrict__ win,
    const float* __restrict__ wout, const float* __restrict__ wah,
    const float* __restrict__ woh, u16* __restrict__ dst) {
  int i = blockIdx.x * 256 + threadIdx.x;
  if (i >= CV_E6) return;
  float4 v;
  if (i < CV_E5) {
    const float* src;
    int base;
    if (i < CV_E0)      { src = f;    base = 0; }
    else if (i < CV_E1) { src = wal;  base = CV_E0; }
    else if (i < CV_E2) { src = wol;  base = CV_E1; }
    else if (i < CV_E3) { src = win;  base = CV_E2; }
    else if (i < CV_E4) { src = wout; base = CV_E3; }
    else                { src = wah;  base = CV_E4; }
    v = ((const float4*)src)[i - base];
  } else {
    // pack: per z, rows 0..1023 = W_in rows 512..1535; rows 1024..1535 = W_oh[z]
    int j = i - CV_E5;
    int z = j / 196608;
    int rem = j - z * 196608;
    int row = rem >> 7, cu = rem & 127;
    if (row < 1024) v = ((const float4*)win)[(512 + row) * 128 + cu];
    else            v = ((const float4*)woh)[z * 65536 + (row - 1024) * 128 + cu];
  }
  ushort4 o;
  o.x = f2bf(v.x); o.y = f2bf(v.y); o.z = f2bf(v.z); o.w = f2bf(v.w);
  ((ushort4*)dst)[i] = o;
}

// ---------- bf16 GEMM v4: no LDS, no barriers ----------
// C[m,n] = act((sum_k A'[m,k]*Bw[n,k] + bias[n]) * scale)
// A' rows: k < ksplit from A (lda), else from A2 (lda2).
// C cols: n < csplit -> C1 (ldc1), else C2 (ldc2). bias split at bsplit.
// ELU applied iff n >= act_split.
// Block = 128x128 tile = 2x2 waves, each wave an independent 64x64 tile.
// MFMA operands loaded straight from global (lane = 16B at
// [m=lane&15][k=(lane>>4)*8]) -> compiler software-pipelines loads across
// k-steps with per-use vmcnt; no __syncthreads anywhere.
// Operand-swapped MFMA: lane owns 4 consecutive cols -> ushort4 stores.
// 1-D grid, XCD swizzle: xcd=flat&7, s=flat>>3, x=s%nx, yz=(s/nx)*8+xcd.
__global__ __launch_bounds__(256) void gemm_v4(
    const u16* __restrict__ A, const u16* __restrict__ A2,
    const u16* __restrict__ Bw,
    u16* __restrict__ C1, u16* __restrict__ C2, int csplit, int ldc1, int ldc2,
    const float* __restrict__ bias1, const float* __restrict__ bias2, int bsplit,
    int K, int ksplit, int lda, int lda2, int ldb,
    long sAz, long sBz, long sC1z, long sC2z, int sb1z, int sb2z,
    float scale, int act_split, int nx) {
  const int wave = threadIdx.x >> 6, lane = threadIdx.x & 63;
  const int l15 = lane & 15, l4 = lane >> 4;

  const int flat = blockIdx.x;
  const int xcd = flat & 7;
  const unsigned s = flat >> 3;
  const int x = s % nx;
  const int yz = (s / nx) * 8 + xcd;
  const int y = yz & 63, z = yz >> 6;
  const int tM = y * 128, tN = x * 128;

  A  += (size_t)z * sAz;
  A2 += (size_t)z * sAz;
  Bw += (size_t)z * sBz;

  const int wr = wave >> 1, wc = wave & 1;
  const int kch = l4 * 8;
  unsigned offA[4], offA2[4], offB[4];
#pragma unroll
  for (int i = 0; i < 4; i++) {
    const int row = tM + wr * 64 + i * 16 + l15;
    offA[i]  = (unsigned)(row * lda) + kch;
    offA2[i] = (unsigned)(row * lda2) + kch;
    const int col = tN + wc * 64 + i * 16 + l15;
    offB[i]  = (unsigned)(col * ldb) + kch;
  }
  const u16* A2b = A2 - ksplit;  // A2b + offA2 + k0 == A2 + row*lda2 + (k0-ksplit) + kch

  f32x4 acc[4][4];
#pragma unroll
  for (int i = 0; i < 4; i++)
#pragma unroll
    for (int j = 0; j < 4; j++) acc[i][j] = (f32x4){0.f, 0.f, 0.f, 0.f};

#pragma unroll 2
  for (int k0 = 0; k0 < K; k0 += 32) {
    const bool first = k0 < ksplit;
    const u16* Ak = (first ? A : A2b) + k0;
    const u16* Bk = Bw + k0;
    bf16x8 af[4], bfv[4];
#pragma unroll
    for (int i = 0; i < 4; i++)
      af[i] = *(const bf16x8*)(Ak + (first ? offA[i] : offA2[i]));
#pragma unroll
    for (int i = 0; i < 4; i++)
      bfv[i] = *(const bf16x8*)(Bk + offB[i]);
#pragma unroll
    for (int mi = 0; mi < 4; mi++)
#pragma unroll
      for (int ni = 0; ni < 4; ni++)
        acc[mi][ni] = __builtin_amdgcn_mfma_f32_16x16x32_bf16(bfv[ni], af[mi], acc[mi][ni], 0, 0, 0);
  }

#pragma unroll
  for (int mi = 0; mi < 4; mi++) {
    const int row = tM + wr * 64 + mi * 16 + l15;
#pragma unroll
    for (int ni = 0; ni < 4; ni++) {
      const int col0 = tN + wc * 64 + ni * 16 + l4 * 4;
      const float* bp = (col0 < bsplit) ? bias1 + (size_t)z * sb1z + col0
                                        : bias2 + (size_t)z * sb2z + (col0 - bsplit);
      float4 bv = *(const float4*)bp;
      f32x4 a = acc[mi][ni];
      float v0 = (a[0] + bv.x) * scale;
      float v1 = (a[1] + bv.y) * scale;
      float v2 = (a[2] + bv.z) * scale;
      float v3 = (a[3] + bv.w) * scale;
      if (col0 >= act_split) {
        v0 = v0 > 0.f ? v0 : (__expf(v0) - 1.f);
        v1 = v1 > 0.f ? v1 : (__expf(v1) - 1.f);
        v2 = v2 > 0.f ? v2 : (__expf(v2) - 1.f);
        v3 = v3 > 0.f ? v3 : (__expf(v3) - 1.f);
      }
      ushort4 st;
      st.x = f2bf(v0); st.y = f2bf(v1); st.z = f2bf(v2); st.w = f2bf(v3);
      u16* cp = (col0 < csplit)
                    ? C1 + (size_t)z * sC1z + (size_t)row * ldc1 + col0
                    : C2 + (size_t)z * sC2z + (size_t)row * ldc2 + (col0 - csplit);
      *(ushort4*)cp = st;
    }
  }
}

// ---------- attention ----------
__global__ __launch_bounds__(256) void attn_kernel(
    const u16* __restrict__ q, const u16* __restrict__ kv,
    u16* __restrict__ attn, float* __restrict__ influ) {
  const int wave = threadIdx.x >> 6, lane = threadIdx.x & 63;
  const int b = blockIdx.x * 4 + wave;
  const size_t qb = (size_t)b * 512;
  float wacc0 = 0.f, wacc1 = 0.f, wacc2 = 0.f;
#pragma unroll
  for (int h = 0; h < 4; ++h) {
    const int off = h * 128 + lane * 2;
    ushort2 qu = *(const ushort2*)(q + qb + off);
    float qx = bf2f(qu.x), qy = bf2f(qu.y);
    float s[3];
#pragma unroll
    for (int o = 0; o < 3; ++o) {
      ushort2 ku = *(const ushort2*)(kv + (size_t)o * (Bsz * 1024) + (size_t)b * 1024 + off);
      float p = qx * bf2f(ku.x) + qy * bf2f(ku.y);
#pragma unroll
      for (int d = 32; d; d >>= 1) p += __shfl_xor(p, d, 64);
      s[o] = p;
    }
    float m = fmaxf(s[0], fmaxf(s[1], s[2]));
    float e0 = __expf(s[0] - m), e1 = __expf(s[1] - m), e2 = __expf(s[2] - m);
    float inv = 1.f / (e0 + e1 + e2);
    float w0 = e0 * inv, w1 = e1 * inv, w2 = e2 * inv;
    wacc0 += w0; wacc1 += w1; wacc2 += w2;
    float ax = 0.f, ay = 0.f;
#pragma unroll
    for (int o = 0; o < 3; ++o) {
      float w = (o == 0) ? w0 : (o == 1) ? w1 : w2;
      ushort2 vu = *(const ushort2*)(kv + (size_t)o * (Bsz * 1024) + (size_t)b * 1024 + 512 + off);
      ax += w * bf2f(vu.x);
      ay += w * bf2f(vu.y);
    }
    ushort2 st; st.x = f2bf(ax); st.y = f2bf(ay);
    *(ushort2*)(attn + qb + off) = st;
  }
  if (lane == 0) {
    influ[b * 3 + 0] = wacc0 * 0.25f;
    influ[b * 3 + 1] = wacc1 * 0.25f;
    influ[b * 3 + 2] = wacc2 * 0.25f;
  }
}

// ---------- final heads ----------
__global__ __launch_bounds__(256) void heads_kernel(
    const u16* __restrict__ ah, const u16* __restrict__ oh,
    const float* __restrict__ Wap, const float* __restrict__ bap,
    const float* __restrict__ Wav, const float* __restrict__ bav,
    const float* __restrict__ Wop, const float* __restrict__ bop,
    const float* __restrict__ Wov, const float* __restrict__ bov,
    float* __restrict__ out) {
  __shared__ float sW[14336];
  for (int i = threadIdx.x; i < 14336; i += 256) {
    int s = i / 3584, rem = i - s * 3584;
    float v;
    if (s == 0) {
      v = (rem < 3072) ? Wap[rem] : Wav[rem - 3072];
    } else {
      int o = s - 1;
      v = (rem < 3072) ? Wop[o * 3072 + rem] : Wov[o * 512 + (rem - 3072)];
    }
    sW[i] = v;
  }
  __syncthreads();
  const int wave = threadIdx.x >> 6, lane = threadIdx.x & 63;
  const int kq = lane & 7, r = lane >> 3;
  const int b = blockIdx.x * 32 + wave * 8 + r;

  const u16* srcs[4] = {ah + (size_t)b * 512,
                        oh + (size_t)b * 512,
                        oh + (size_t)(Bsz + b) * 512,
                        oh + (size_t)(2 * Bsz + b) * 512};
  bf16x8 a[4][8];
#pragma unroll
  for (int s = 0; s < 4; s++)
#pragma unroll
    for (int c = 0; c < 8; c++)
      a[s][c] = *(const bf16x8*)(srcs[s] + c * 64 + kq * 8);

#pragma unroll
  for (int s = 0; s < 4; s++) {
#pragma unroll
    for (int p = 0; p < 7; p++) {
      const float* w = &sW[s * 3584 + p * 512 + kq * 8];
      float acc = 0.f;
#pragma unroll
      for (int c = 0; c < 8; c++) {
#pragma unroll
        for (int j = 0; j < 8; j++)
          acc += (float)a[s][c][j] * w[c * 64 + j];
      }
      acc += __shfl_xor(acc, 1, 64);
      acc += __shfl_xor(acc, 2, 64);
      acc += __shfl_xor(acc, 4, 64);
      if (kq == p) {
        if (s == 0) {
          if (p < 6) out[OUT_AP + b * 6 + p] = acc + bap[p];
          else       out[OUT_AV + b] = acc + bav[0];
        } else {
          int o = s - 1;
          if (p < 6) out[OUT_OP + b * 18 + o * 6 + p] = acc + bop[o * 6 + p];
          else       out[OUT_OV + b * 3 + o] = acc + bov[o];
        }
      }
    }
  }
}

extern "C" void kernel_launch(void* const* d_in, const int* in_sizes, int n_in,
                              void* d_out, int out_size, void* d_ws, size_t ws_size,
                              hipStream_t stream) {
  (void)in_sizes; (void)n_in; (void)out_size; (void)ws_size;
  const float* f     = (const float*)d_in[0];
  const float* W_al  = (const float*)d_in[1];
  const float* b_al  = (const float*)d_in[2];
  const float* W_in  = (const float*)d_in[3];
  const float* b_in  = (const float*)d_in[4];
  const float* W_out = (const float*)d_in[5];
  const float* b_out = (const float*)d_in[6];
  const float* W_ah  = (const float*)d_in[7];
  const float* b_ah  = (const float*)d_in[8];
  const float* W_ap  = (const float*)d_in[9];
  const float* b_ap  = (const float*)d_in[10];
  const float* W_av  = (const float*)d_in[11];
  const float* b_av  = (const float*)d_in[12];
  const float* W_ol  = (const float*)d_in[13];
  const float* b_ol  = (const float*)d_in[14];
  const float* W_oh  = (const float*)d_in[15];
  const float* b_oh  = (const float*)d_in[16];
  const float* W_op  = (const float*)d_in[17];
  const float* b_op  = (const float*)d_in[18];
  const float* W_ov  = (const float*)d_in[19];
  const float* b_ov  = (const float*)d_in[20];
  float* out = (float*)d_out;
  u16* ws = (u16*)d_ws;

  u16* feat  = ws + OFF_FEAT;
  u16* wcomb = ws + OFF_WCOMB;
  u16* wq    = ws + OFF_WQ;
  u16* wout  = ws + OFF_WOUT;
  u16* wah   = ws + OFF_WAH;
  u16* pack  = ws + OFF_PACK;
  u16* lat   = ws + OFF_LAT;
  u16* qb    = ws + OFF_Q;
  u16* kvb   = ws + OFF_KV;
  u16* att   = ws + OFF_ATT;
  u16* ao    = ws + OFF_AO;
  u16* agh   = ws + OFF_Q;   // reuse q's slot after attention
  u16* oph   = ws + OFF_OPH;

  convert_all<<<13568, 256, 0, stream>>>(f, W_al, W_ol, W_in, W_out, W_ah, W_oh, ws);

  // lat = elu(feat @ [W_al;W_ol]^T + [b_al;b_ol])  (B x 2048)
  gemm_v4<<<1024, 256, 0, stream>>>(
      feat, feat, wcomb, lat, lat, BIGI, 2048, 2048,
      b_al, b_ol, 512, 1024, BIGI, 1024, 1024, 1024,
      0, 0, 0, 0, 0, 0, 1.f, 0, 16);
  // q = (agent_latent @ Wq^T + bq) / sqrt(128)
  gemm_v4<<<256, 256, 0, stream>>>(
      lat, lat, wq, qb, qb, BIGI, 512, 512,
      b_in, b_in, BIGI, 512, BIGI, 2048, 2048, 512,
      0, 0, 0, 0, 0, 0, 0.08838834764831845f, BIGI, 4);
  // merged kv + opp_heads: A = opp_lat[z], B = [Wk;Wv;W_oh[z]] (N=1536)
  // cols 0..1023 -> kvb[z] (no act), cols 1024..1535 -> oph[z] (ELU)
  gemm_v4<<<2304, 256, 0, stream>>>(
      lat + 512, lat + 512, pack, kvb, oph, 1024, 1024, 512,
      b_in + 512, b_oh, 1024, 512, BIGI, 2048, 2048, 512,
      512, 786432, 8388608, 4194304, 0, 512, 1.f, 1024, 12);

  attn_kernel<<<2048, 256, 0, stream>>>(qb, kvb, att, out + OUT_IN);

  // attn_out = attn @ W_out^T + b_out
  gemm_v4<<<256, 256, 0, stream>>>(
      att, att, wout, ao, ao, BIGI, 512, 512,
      b_out, b_out, BIGI, 512, BIGI, 512, 512, 512,
      0, 0, 0, 0, 0, 0, 1.f, BIGI, 4);
  // agent_head = elu([agent_latent | attn_out] @ W_ah^T + b_ah)  (split-A)
  gemm_v4<<<256, 256, 0, stream>>>(
      lat, ao, wah, agh, agh, BIGI, 512, 512,
      b_ah, b_ah, BIGI, 1024, 512, 2048, 512, 1024,
      0, 0, 0, 0, 0, 0, 1.f, 0, 4);

  heads_kernel<<<256, 256, 0, stream>>>(agh, oph, W_ap, b_ap, W_av, b_av,
                                        W_op, b_op, W_ov, b_ov, out);
}

// Round 6
// 364.393 us; speedup vs baseline: 1.3573x; 1.3573x over previous
//
#include <hip/hip_runtime.h>

typedef unsigned short u16;
typedef __bf16 bf16x8 __attribute__((ext_vector_type(8)));
typedef float f32x4 __attribute__((ext_vector_type(4)));

#define Bsz 8192
#define BIGI (1 << 30)

// ws element offsets (u16 elements)
#define OFF_FEAT   0
#define OFF_WCOMB  8388608    // [W_al (512x1024) | W_ol (1536x1024)]
#define OFF_WQ     10485760   // 512x512 (W_in rows 0..511)
#define OFF_WOUT   10747904   // 512x512
#define OFF_WAH    11010048   // 512x1024
#define OFF_PACK   11534336   // 3 x 1536x512 : [Wk; Wv; W_oh[z]]
#define OFF_LAT    13893632   // B x 2048 : [agent | opp0 | opp1 | opp2]
#define OFF_Q      30670848   // B x 512 (later reused for agent_head)
#define OFF_KV     34865152   // 3 x B x 1024 : [k | v]
#define OFF_ATT    60030976   // B x 512
#define OFF_AO     64225280   // B x 512
#define OFF_OPH    68419584   // 3 x B x 512

// d_out offsets (fp32 elements)
#define OUT_AP 0
#define OUT_AV 49152
#define OUT_OP 57344
#define OUT_OV 204800
#define OUT_IN 229376

__device__ __forceinline__ u16 f2bf(float f) {
  return __builtin_bit_cast(u16, (__bf16)f);
}
__device__ __forceinline__ float bf2f(u16 u) {
  return (float)__builtin_bit_cast(__bf16, u);
}

__device__ __forceinline__ void gload16(const u16* g, u16* s) {
  __builtin_amdgcn_global_load_lds(
      (const __attribute__((address_space(1))) unsigned int*)g,
      (__attribute__((address_space(3))) unsigned int*)s, 16, 0, 0);
}

// ---------- fp32 -> bf16 conversion + B-pack build ----------
#define CV_E0 2097152
#define CV_E1 2228224
#define CV_E2 2621440
#define CV_E3 2686976
#define CV_E4 2752512
#define CV_E5 2883584
#define CV_E6 3473408
__global__ __launch_bounds__(256) void convert_all(
    const float* __restrict__ f, const float* __restrict__ wal,
    const float* __restrict__ wol, const float* __restrict__ win,
    const float* __restrict__ wout, const float* __restrict__ wah,
    const float* __restrict__ woh, u16* __restrict__ dst) {
  int i = blockIdx.x * 256 + threadIdx.x;
  if (i >= CV_E6) return;
  float4 v;
  if (i < CV_E5) {
    const float* src;
    int base;
    if (i < CV_E0)      { src = f;    base = 0; }
    else if (i < CV_E1) { src = wal;  base = CV_E0; }
    else if (i < CV_E2) { src = wol;  base = CV_E1; }
    else if (i < CV_E3) { src = win;  base = CV_E2; }
    else if (i < CV_E4) { src = wout; base = CV_E3; }
    else                { src = wah;  base = CV_E4; }
    v = ((const float4*)src)[i - base];
  } else {
    // pack: per z, rows 0..1023 = W_in rows 512..1535; rows 1024..1535 = W_oh[z]
    int j = i - CV_E5;
    int z = j / 196608;
    int rem = j - z * 196608;
    int row = rem >> 7, cu = rem & 127;
    if (row < 1024) v = ((const float4*)win)[(512 + row) * 128 + cu];
    else            v = ((const float4*)woh)[z * 65536 + (row - 1024) * 128 + cu];
  }
  ushort4 o;
  o.x = f2bf(v.x); o.y = f2bf(v.y); o.z = f2bf(v.z); o.w = f2bf(v.w);
  ((ushort4*)dst)[i] = o;
}

// ---------- bf16 GEMM v3: 128-col, BM=64, 256 thr (for N=512 GEMMs) ----------
template <int BM>
__global__ __launch_bounds__(256) void gemm_v3(
    const u16* __restrict__ A, const u16* __restrict__ A2,
    const u16* __restrict__ Bw,
    u16* __restrict__ C1, u16* __restrict__ C2, int csplit, int ldc1, int ldc2,
    const float* __restrict__ bias1, const float* __restrict__ bias2, int bsplit,
    int K, int ksplit, int lda, int lda2, int ldb,
    long sAz, long sBz, long sC1z, long sC2z, int sb1z, int sb2z,
    float scale, int act_split, int nx) {
  constexpr int nA = BM / 16;
  constexpr int NFR = nA + 8;
  constexpr int FPW = NFR / 4;
  constexpr int MI = BM / 32;
  constexpr int SB = nA * 512;
  __shared__ __align__(16) u16 S[NFR * 512];
  const int wave = threadIdx.x >> 6, lane = threadIdx.x & 63;
  const int l15 = lane & 15, l4 = lane >> 4;

  const int flat = blockIdx.x;
  const int xcd = flat & 7;
  const unsigned s = flat >> 3;
  const int x = s % nx;
  const int yz = (s / nx) * 8 + xcd;
  constexpr int NY = 8192 / BM;
  const int y = yz & (NY - 1), z = yz / NY;
  const int tM = y * BM, tN = x * 128;

  A  += (size_t)z * sAz;
  A2 += (size_t)z * sAz;
  Bw += (size_t)z * sBz;
  const u16* p1[FPW];
  const u16* p2[FPW];
  u16* dst[FPW];
  int kspl[FPW];
  const int kch = l4 * 8;
#pragma unroll
  for (int t = 0; t < FPW; ++t) {
    const int fr = wave * FPW + t;
    if (fr < nA) {
      const int row = tM + fr * 16 + l15;
      p1[t] = A + (size_t)row * lda + kch;
      p2[t] = A2 + ((long)row * lda2 + kch - ksplit);
      dst[t] = &S[fr * 512];
      kspl[t] = ksplit;
    } else {
      const int g = fr - nA;
      const int row = tN + g * 16 + l15;
      p1[t] = Bw + (size_t)row * ldb + kch;
      p2[t] = p1[t];
      dst[t] = &S[SB + g * 512];
      kspl[t] = BIGI;
    }
  }

  const int wr = wave >> 1, wc = wave & 1;
  f32x4 acc[MI][4];
#pragma unroll
  for (int i = 0; i < MI; i++)
#pragma unroll
    for (int j = 0; j < 4; j++) acc[i][j] = (f32x4){0.f, 0.f, 0.f, 0.f};

  for (int k0 = 0; k0 < K; k0 += 32) {
    __syncthreads();
#pragma unroll
    for (int t = 0; t < FPW; ++t)
      gload16((k0 < kspl[t] ? p1[t] : p2[t]) + k0, dst[t]);
    __syncthreads();
    bf16x8 af[MI], bfr[4];
#pragma unroll
    for (int mi = 0; mi < MI; mi++)
      af[mi] = *(const bf16x8*)&S[(wr * MI + mi) * 512 + lane * 8];
#pragma unroll
    for (int ni = 0; ni < 4; ni++)
      bfr[ni] = *(const bf16x8*)&S[SB + (wc * 4 + ni) * 512 + lane * 8];
#pragma unroll
    for (int mi = 0; mi < MI; mi++)
#pragma unroll
      for (int ni = 0; ni < 4; ni++)
        acc[mi][ni] = __builtin_amdgcn_mfma_f32_16x16x32_bf16(bfr[ni], af[mi], acc[mi][ni], 0, 0, 0);
  }

#pragma unroll
  for (int mi = 0; mi < MI; mi++) {
    const int row = tM + wr * (BM / 2) + mi * 16 + l15;
#pragma unroll
    for (int ni = 0; ni < 4; ni++) {
      const int col0 = tN + wc * 64 + ni * 16 + l4 * 4;
      const float* bp = (col0 < bsplit) ? bias1 + (size_t)z * sb1z + col0
                                        : bias2 + (size_t)z * sb2z + (col0 - bsplit);
      float4 bv = *(const float4*)bp;
      f32x4 a = acc[mi][ni];
      float v0 = (a[0] + bv.x) * scale;
      float v1 = (a[1] + bv.y) * scale;
      float v2 = (a[2] + bv.z) * scale;
      float v3 = (a[3] + bv.w) * scale;
      if (col0 >= act_split) {
        v0 = v0 > 0.f ? v0 : (__expf(v0) - 1.f);
        v1 = v1 > 0.f ? v1 : (__expf(v1) - 1.f);
        v2 = v2 > 0.f ? v2 : (__expf(v2) - 1.f);
        v3 = v3 > 0.f ? v3 : (__expf(v3) - 1.f);
      }
      ushort4 st;
      st.x = f2bf(v0); st.y = f2bf(v1); st.z = f2bf(v2); st.w = f2bf(v3);
      u16* cp = (col0 < csplit)
                    ? C1 + (size_t)z * sC1z + (size_t)row * ldc1 + col0
                    : C2 + (size_t)z * sC2z + (size_t)row * ldc2 + (col0 - csplit);
      *(ushort4*)cp = st;
    }
  }
}

// ---------- bf16 GEMM v5: 256x128 tile, 512 thr (8 waves 4x2), BK=32 ----------
// 24 KB LDS/step (16 A frags + 8 B frags), 3 gload16 per wave, 2 blocks/CU.
// 87 FLOP per staged byte (vs 64 for 128x128) to beat the staging ceiling.
__global__ __launch_bounds__(512, 4) void gemm_v5(
    const u16* __restrict__ A, const u16* __restrict__ Bw,
    u16* __restrict__ C1, u16* __restrict__ C2, int csplit, int ldc1, int ldc2,
    const float* __restrict__ bias1, const float* __restrict__ bias2, int bsplit,
    int K, int lda, int ldb,
    long sAz, long sBz, long sC1z, long sC2z, int sb1z, int sb2z,
    float scale, int act_split, int nx) {
  __shared__ __align__(16) u16 S[12288];  // A 0..8191, B 8192..12287
  const int wave = threadIdx.x >> 6, lane = threadIdx.x & 63;
  const int l15 = lane & 15, l4 = lane >> 4;

  const int flat = blockIdx.x;
  const int xcd = flat & 7;
  const unsigned s = flat >> 3;
  const int x = s % nx;
  const int yz = (s / nx) * 8 + xcd;
  const int y = yz & 31, z = yz >> 5;
  const int tM = y * 256, tN = x * 128;

  A  += (size_t)z * sAz;
  Bw += (size_t)z * sBz;

  const int kch = l4 * 8;
  const u16* src[3];
  u16* dst[3];
#pragma unroll
  for (int t = 0; t < 3; ++t) {
    const int fr = wave * 3 + t;
    if (fr < 16) {
      src[t] = A + (size_t)(tM + fr * 16 + l15) * lda + kch;
      dst[t] = &S[fr * 512];
    } else {
      const int g = fr - 16;
      src[t] = Bw + (size_t)(tN + g * 16 + l15) * ldb + kch;
      dst[t] = &S[8192 + g * 512];
    }
  }

  const int wr = wave >> 1, wc = wave & 1;
  f32x4 acc[4][4];
#pragma unroll
  for (int i = 0; i < 4; i++)
#pragma unroll
    for (int j = 0; j < 4; j++) acc[i][j] = (f32x4){0.f, 0.f, 0.f, 0.f};

  for (int k0 = 0; k0 < K; k0 += 32) {
    __syncthreads();
#pragma unroll
    for (int t = 0; t < 3; ++t)
      gload16(src[t] + k0, dst[t]);
    __syncthreads();
    bf16x8 af[4], bfr[4];
#pragma unroll
    for (int mi = 0; mi < 4; mi++)
      af[mi] = *(const bf16x8*)&S[(wr * 4 + mi) * 512 + lane * 8];
#pragma unroll
    for (int ni = 0; ni < 4; ni++)
      bfr[ni] = *(const bf16x8*)&S[8192 + (wc * 4 + ni) * 512 + lane * 8];
#pragma unroll
    for (int mi = 0; mi < 4; mi++)
#pragma unroll
      for (int ni = 0; ni < 4; ni++)
        acc[mi][ni] = __builtin_amdgcn_mfma_f32_16x16x32_bf16(bfr[ni], af[mi], acc[mi][ni], 0, 0, 0);
  }

#pragma unroll
  for (int mi = 0; mi < 4; mi++) {
    const int row = tM + wr * 64 + mi * 16 + l15;
#pragma unroll
    for (int ni = 0; ni < 4; ni++) {
      const int col0 = tN + wc * 64 + ni * 16 + l4 * 4;
      const float* bp = (col0 < bsplit) ? bias1 + (size_t)z * sb1z + col0
                                        : bias2 + (size_t)z * sb2z + (col0 - bsplit);
      float4 bv = *(const float4*)bp;
      f32x4 a = acc[mi][ni];
      float v0 = (a[0] + bv.x) * scale;
      float v1 = (a[1] + bv.y) * scale;
      float v2 = (a[2] + bv.z) * scale;
      float v3 = (a[3] + bv.w) * scale;
      if (col0 >= act_split) {
        v0 = v0 > 0.f ? v0 : (__expf(v0) - 1.f);
        v1 = v1 > 0.f ? v1 : (__expf(v1) - 1.f);
        v2 = v2 > 0.f ? v2 : (__expf(v2) - 1.f);
        v3 = v3 > 0.f ? v3 : (__expf(v3) - 1.f);
      }
      ushort4 st;
      st.x = f2bf(v0); st.y = f2bf(v1); st.z = f2bf(v2); st.w = f2bf(v3);
      u16* cp = (col0 < csplit)
                    ? C1 + (size_t)z * sC1z + (size_t)row * ldc1 + col0
                    : C2 + (size_t)z * sC2z + (size_t)row * ldc2 + (col0 - csplit);
      *(ushort4*)cp = st;
    }
  }
}

// ---------- attention ----------
__global__ __launch_bounds__(256) void attn_kernel(
    const u16* __restrict__ q, const u16* __restrict__ kv,
    u16* __restrict__ attn, float* __restrict__ influ) {
  const int wave = threadIdx.x >> 6, lane = threadIdx.x & 63;
  const int b = blockIdx.x * 4 + wave;
  const size_t qb = (size_t)b * 512;
  float wacc0 = 0.f, wacc1 = 0.f, wacc2 = 0.f;
#pragma unroll
  for (int h = 0; h < 4; ++h) {
    const int off = h * 128 + lane * 2;
    ushort2 qu = *(const ushort2*)(q + qb + off);
    float qx = bf2f(qu.x), qy = bf2f(qu.y);
    float s[3];
#pragma unroll
    for (int o = 0; o < 3; ++o) {
      ushort2 ku = *(const ushort2*)(kv + (size_t)o * (Bsz * 1024) + (size_t)b * 1024 + off);
      float p = qx * bf2f(ku.x) + qy * bf2f(ku.y);
#pragma unroll
      for (int d = 32; d; d >>= 1) p += __shfl_xor(p, d, 64);
      s[o] = p;
    }
    float m = fmaxf(s[0], fmaxf(s[1], s[2]));
    float e0 = __expf(s[0] - m), e1 = __expf(s[1] - m), e2 = __expf(s[2] - m);
    float inv = 1.f / (e0 + e1 + e2);
    float w0 = e0 * inv, w1 = e1 * inv, w2 = e2 * inv;
    wacc0 += w0; wacc1 += w1; wacc2 += w2;
    float ax = 0.f, ay = 0.f;
#pragma unroll
    for (int o = 0; o < 3; ++o) {
      float w = (o == 0) ? w0 : (o == 1) ? w1 : w2;
      ushort2 vu = *(const ushort2*)(kv + (size_t)o * (Bsz * 1024) + (size_t)b * 1024 + 512 + off);
      ax += w * bf2f(vu.x);
      ay += w * bf2f(vu.y);
    }
    ushort2 st; st.x = f2bf(ax); st.y = f2bf(ay);
    *(ushort2*)(attn + qb + off) = st;
  }
  if (lane == 0) {
    influ[b * 3 + 0] = wacc0 * 0.25f;
    influ[b * 3 + 1] = wacc1 * 0.25f;
    influ[b * 3 + 2] = wacc2 * 0.25f;
  }
}

// ---------- final heads ----------
__global__ __launch_bounds__(256) void heads_kernel(
    const u16* __restrict__ ah, const u16* __restrict__ oh,
    const float* __restrict__ Wap, const float* __restrict__ bap,
    const float* __restrict__ Wav, const float* __restrict__ bav,
    const float* __restrict__ Wop, const float* __restrict__ bop,
    const float* __restrict__ Wov, const float* __restrict__ bov,
    float* __restrict__ out) {
  __shared__ float sW[14336];
  for (int i = threadIdx.x; i < 14336; i += 256) {
    int s = i / 3584, rem = i - s * 3584;
    float v;
    if (s == 0) {
      v = (rem < 3072) ? Wap[rem] : Wav[rem - 3072];
    } else {
      int o = s - 1;
      v = (rem < 3072) ? Wop[o * 3072 + rem] : Wov[o * 512 + (rem - 3072)];
    }
    sW[i] = v;
  }
  __syncthreads();
  const int wave = threadIdx.x >> 6, lane = threadIdx.x & 63;
  const int kq = lane & 7, r = lane >> 3;
  const int b = blockIdx.x * 32 + wave * 8 + r;

  const u16* srcs[4] = {ah + (size_t)b * 512,
                        oh + (size_t)b * 512,
                        oh + (size_t)(Bsz + b) * 512,
                        oh + (size_t)(2 * Bsz + b) * 512};
  bf16x8 a[4][8];
#pragma unroll
  for (int s = 0; s < 4; s++)
#pragma unroll
    for (int c = 0; c < 8; c++)
      a[s][c] = *(const bf16x8*)(srcs[s] + c * 64 + kq * 8);

#pragma unroll
  for (int s = 0; s < 4; s++) {
#pragma unroll
    for (int p = 0; p < 7; p++) {
      const float* w = &sW[s * 3584 + p * 512 + kq * 8];
      float acc = 0.f;
#pragma unroll
      for (int c = 0; c < 8; c++) {
#pragma unroll
        for (int j = 0; j < 8; j++)
          acc += (float)a[s][c][j] * w[c * 64 + j];
      }
      acc += __shfl_xor(acc, 1, 64);
      acc += __shfl_xor(acc, 2, 64);
      acc += __shfl_xor(acc, 4, 64);
      if (kq == p) {
        if (s == 0) {
          if (p < 6) out[OUT_AP + b * 6 + p] = acc + bap[p];
          else       out[OUT_AV + b] = acc + bav[0];
        } else {
          int o = s - 1;
          if (p < 6) out[OUT_OP + b * 18 + o * 6 + p] = acc + bop[o * 6 + p];
          else       out[OUT_OV + b * 3 + o] = acc + bov[o];
        }
      }
    }
  }
}

extern "C" void kernel_launch(void* const* d_in, const int* in_sizes, int n_in,
                              void* d_out, int out_size, void* d_ws, size_t ws_size,
                              hipStream_t stream) {
  (void)in_sizes; (void)n_in; (void)out_size; (void)ws_size;
  const float* f     = (const float*)d_in[0];
  const float* W_al  = (const float*)d_in[1];
  const float* b_al  = (const float*)d_in[2];
  const float* W_in  = (const float*)d_in[3];
  const float* b_in  = (const float*)d_in[4];
  const float* W_out = (const float*)d_in[5];
  const float* b_out = (const float*)d_in[6];
  const float* W_ah  = (const float*)d_in[7];
  const float* b_ah  = (const float*)d_in[8];
  const float* W_ap  = (const float*)d_in[9];
  const float* b_ap  = (const float*)d_in[10];
  const float* W_av  = (const float*)d_in[11];
  const float* b_av  = (const float*)d_in[12];
  const float* W_ol  = (const float*)d_in[13];
  const float* b_ol  = (const float*)d_in[14];
  const float* W_oh  = (const float*)d_in[15];
  const float* b_oh  = (const float*)d_in[16];
  const float* W_ap_ = W_ap;
  const float* W_op  = (const float*)d_in[17];
  const float* b_op  = (const float*)d_in[18];
  const float* W_ov  = (const float*)d_in[19];
  const float* b_ov  = (const float*)d_in[20];
  (void)W_ap_;
  float* out = (float*)d_out;
  u16* ws = (u16*)d_ws;

  u16* feat  = ws + OFF_FEAT;
  u16* wcomb = ws + OFF_WCOMB;
  u16* wq    = ws + OFF_WQ;
  u16* wout  = ws + OFF_WOUT;
  u16* wah   = ws + OFF_WAH;
  u16* pack  = ws + OFF_PACK;
  u16* lat   = ws + OFF_LAT;
  u16* qb    = ws + OFF_Q;
  u16* kvb   = ws + OFF_KV;
  u16* att   = ws + OFF_ATT;
  u16* ao    = ws + OFF_AO;
  u16* agh   = ws + OFF_Q;   // reuse q's slot after attention
  u16* oph   = ws + OFF_OPH;

  convert_all<<<13568, 256, 0, stream>>>(f, W_al, W_ol, W_in, W_out, W_ah, W_oh, ws);

  // lat = elu(feat @ [W_al;W_ol]^T + [b_al;b_ol])  (B x 2048), 256x128 tiles
  gemm_v5<<<512, 512, 0, stream>>>(
      feat, wcomb, lat, lat, BIGI, 2048, 2048,
      b_al, b_ol, 512, 1024, 1024, 1024,
      0, 0, 0, 0, 0, 0, 1.f, 0, 16);
  // q = (agent_latent @ Wq^T + bq) / sqrt(128)
  gemm_v3<64><<<512, 256, 0, stream>>>(
      lat, lat, wq, qb, qb, BIGI, 512, 512,
      b_in, b_in, BIGI, 512, BIGI, 2048, 2048, 512,
      0, 0, 0, 0, 0, 0, 0.08838834764831845f, BIGI, 4);
  // merged kv + opp_heads: A = opp_lat[z], B = [Wk;Wv;W_oh[z]] (N=1536)
  gemm_v5<<<1152, 512, 0, stream>>>(
      lat + 512, pack, kvb, oph, 1024, 1024, 512,
      b_in + 512, b_oh, 1024, 512, 2048, 512,
      512, 786432, 8388608, 4194304, 0, 512, 1.f, 1024, 12);

  attn_kernel<<<2048, 256, 0, stream>>>(qb, kvb, att, out + OUT_IN);

  // attn_out = attn @ W_out^T + b_out
  gemm_v3<64><<<512, 256, 0, stream>>>(
      att, att, wout, ao, ao, BIGI, 512, 512,
      b_out, b_out, BIGI, 512, BIGI, 512, 512, 512,
      0, 0, 0, 0, 0, 0, 1.f, BIGI, 4);
  // agent_head = elu([agent_latent | attn_out] @ W_ah^T + b_ah)  (split-A)
  gemm_v3<64><<<512, 256, 0, stream>>>(
      lat, ao, wah, agh, agh, BIGI, 512, 512,
      b_ah, b_ah, BIGI, 1024, 512, 2048, 512, 1024,
      0, 0, 0, 0, 0, 0, 1.f, 0, 4);

  heads_kernel<<<256, 256, 0, stream>>>(agh, oph, W_ap, b_ap, W_av, b_av,
                                        W_op, b_op, W_ov, b_ov, out);
}

// Round 7
// 363.960 us; speedup vs baseline: 1.3589x; 1.0012x over previous
//
#include <hip/hip_runtime.h>

typedef unsigned short u16;
typedef __bf16 bf16x8 __attribute__((ext_vector_type(8)));
typedef float f32x4 __attribute__((ext_vector_type(4)));

#define Bsz 8192
#define BIGI (1 << 30)

// ws element offsets (u16 elements)
#define OFF_FEAT   0
#define OFF_WCOMB  8388608    // [W_al (512x1024) | W_ol (1536x1024)]
#define OFF_WQ     10485760   // 512x512 (W_in rows 0..511)
#define OFF_WOUT   10747904   // 512x512
#define OFF_WAH    11010048   // 512x1024
#define OFF_PACK   11534336   // 3 x 1536x512 : [Wk; Wv; W_oh[z]]
#define OFF_LAT    13893632   // B x 2048 : [agent | opp0 | opp1 | opp2]
#define OFF_Q      30670848   // B x 512 (later reused for agent_head)
#define OFF_KV     34865152   // 3 x B x 1024 : [k | v]
#define OFF_ATT    60030976   // B x 512
#define OFF_AO     64225280   // B x 512
#define OFF_OPH    68419584   // 3 x B x 512

// d_out offsets (fp32 elements)
#define OUT_AP 0
#define OUT_AV 49152
#define OUT_OP 57344
#define OUT_OV 204800
#define OUT_IN 229376

__device__ __forceinline__ u16 f2bf(float f) {
  return __builtin_bit_cast(u16, (__bf16)f);
}
__device__ __forceinline__ float bf2f(u16 u) {
  return (float)__builtin_bit_cast(__bf16, u);
}

__device__ __forceinline__ void gload16(const u16* g, u16* s) {
  __builtin_amdgcn_global_load_lds(
      (const __attribute__((address_space(1))) unsigned int*)g,
      (__attribute__((address_space(3))) unsigned int*)s, 16, 0, 0);
}

// ---------- fp32 -> bf16 conversion + B-pack build ----------
#define CV_E0 2097152
#define CV_E1 2228224
#define CV_E2 2621440
#define CV_E3 2686976
#define CV_E4 2752512
#define CV_E5 2883584
#define CV_E6 3473408
__global__ __launch_bounds__(256) void convert_all(
    const float* __restrict__ f, const float* __restrict__ wal,
    const float* __restrict__ wol, const float* __restrict__ win,
    const float* __restrict__ wout, const float* __restrict__ wah,
    const float* __restrict__ woh, u16* __restrict__ dst) {
  int i = blockIdx.x * 256 + threadIdx.x;
  if (i >= CV_E6) return;
  float4 v;
  if (i < CV_E5) {
    const float* src;
    int base;
    if (i < CV_E0)      { src = f;    base = 0; }
    else if (i < CV_E1) { src = wal;  base = CV_E0; }
    else if (i < CV_E2) { src = wol;  base = CV_E1; }
    else if (i < CV_E3) { src = win;  base = CV_E2; }
    else if (i < CV_E4) { src = wout; base = CV_E3; }
    else                { src = wah;  base = CV_E4; }
    v = ((const float4*)src)[i - base];
  } else {
    // pack: per z, rows 0..1023 = W_in rows 512..1535; rows 1024..1535 = W_oh[z]
    int j = i - CV_E5;
    int z = j / 196608;
    int rem = j - z * 196608;
    int row = rem >> 7, cu = rem & 127;
    if (row < 1024) v = ((const float4*)win)[(512 + row) * 128 + cu];
    else            v = ((const float4*)woh)[z * 65536 + (row - 1024) * 128 + cu];
  }
  ushort4 o;
  o.x = f2bf(v.x); o.y = f2bf(v.y); o.z = f2bf(v.z); o.w = f2bf(v.w);
  ((ushort4*)dst)[i] = o;
}

// ---------- bf16 GEMM v6: 128x128, BK=64, 256 thr, 4 blocks/CU target ----------
// Optional "q-job": blocks flat < qnb run a second GEMM geometry (same K,
// lda, ldb reused where equal). Merged C-split: n<csplit -> C1 else C2;
// bias split at bsplit; ELU iff n >= act_split.
// Fragment-ordered LDS (conflict-free): chunk = rowfrag*2 + khalf, 1 KB each.
// Operand-swapped MFMA: lane owns 4 consecutive cols -> ushort4 stores.
__global__ __launch_bounds__(256, 4) void gemm_v6(
    const u16* __restrict__ A, const u16* __restrict__ Bw,
    u16* __restrict__ C1, u16* __restrict__ C2, int csplit, int ldc1, int ldc2,
    const float* __restrict__ bias1, const float* __restrict__ bias2, int bsplit,
    int K, int lda, int ldb,
    long sAz, long sBz, long sC1z, long sC2z, int sb2z,
    float scale, int act_split, int nx,
    int qnb, const u16* __restrict__ Aq, const u16* __restrict__ Bq,
    u16* __restrict__ Cq, const float* __restrict__ biasq, float scaleq) {
  __shared__ __align__(16) u16 S[16384];  // 32 KB: A chunks 0..15, B chunks 16..31
  const int wave = threadIdx.x >> 6, lane = threadIdx.x & 63;
  const int l15 = lane & 15, l4 = lane >> 4;

  const int flat = blockIdx.x;
  int x, y, z, csp, lc1, lc2, bsp, asp;
  const u16 *Ab, *Bb;
  u16 *C1b, *C2b;
  const float *b1, *b2;
  float sc;
  if (flat < qnb) {
    x = flat & 3; y = flat >> 2; z = 0;
    Ab = Aq; Bb = Bq; C1b = Cq; C2b = Cq; b1 = biasq; b2 = biasq;
    csp = BIGI; lc1 = 512; lc2 = 512; bsp = BIGI; asp = BIGI; sc = scaleq;
  } else {
    const int f2 = flat - qnb;
    const int xcd = f2 & 7;
    const unsigned s = f2 >> 3;
    x = s % nx;
    const int yz = (s / nx) * 8 + xcd;
    y = yz & 63; z = yz >> 6;
    Ab = A + (size_t)z * sAz; Bb = Bw + (size_t)z * sBz;
    C1b = C1 + (size_t)z * sC1z; C2b = C2 + (size_t)z * sC2z;
    b1 = bias1; b2 = bias2 + (size_t)z * sb2z;
    csp = csplit; lc1 = ldc1; lc2 = ldc2; bsp = bsplit; asp = act_split;
    sc = scale;
  }
  const int tM = y * 128, tN = x * 128;

  // staging: waves 0,1 stage A rowfrags, waves 2,3 stage B rowfrags.
  // Each wave: 4 rowfrags x 2 k-halves = 8 gload16 per 64-k step.
  const bool isA = wave < 2;
  const int half = isA ? wave : wave - 2;
  const u16* base = isA ? Ab : Bb;
  const int ld = isA ? lda : ldb;
  const int t0 = isA ? tM : tN;
  const int kch = l4 * 8;
  unsigned off[4];
#pragma unroll
  for (int t = 0; t < 4; ++t)
    off[t] = (unsigned)((t0 + half * 64 + t * 16 + l15) * ld) + kch;
  u16* dst0 = &S[(isA ? 0 : 8192) + half * 4096];

  const int wr = wave >> 1, wc = wave & 1;
  f32x4 acc[4][4];
#pragma unroll
  for (int i = 0; i < 4; i++)
#pragma unroll
    for (int j = 0; j < 4; j++) acc[i][j] = (f32x4){0.f, 0.f, 0.f, 0.f};

  for (int k0 = 0; k0 < K; k0 += 64) {
    __syncthreads();
#pragma unroll
    for (int t = 0; t < 4; ++t) {
      gload16(base + off[t] + k0, dst0 + t * 1024);
      gload16(base + off[t] + k0 + 32, dst0 + t * 1024 + 512);
    }
    __syncthreads();
#pragma unroll
    for (int h = 0; h < 2; ++h) {
      bf16x8 af[4], bfr[4];
#pragma unroll
      for (int mi = 0; mi < 4; mi++)
        af[mi] = *(const bf16x8*)&S[(wr * 4 + mi) * 1024 + h * 512 + lane * 8];
#pragma unroll
      for (int ni = 0; ni < 4; ni++)
        bfr[ni] = *(const bf16x8*)&S[8192 + (wc * 4 + ni) * 1024 + h * 512 + lane * 8];
#pragma unroll
      for (int mi = 0; mi < 4; mi++)
#pragma unroll
        for (int ni = 0; ni < 4; ni++)
          acc[mi][ni] = __builtin_amdgcn_mfma_f32_16x16x32_bf16(bfr[ni], af[mi], acc[mi][ni], 0, 0, 0);
    }
  }

#pragma unroll
  for (int mi = 0; mi < 4; mi++) {
    const int row = tM + wr * 64 + mi * 16 + l15;
#pragma unroll
    for (int ni = 0; ni < 4; ni++) {
      const int col0 = tN + wc * 64 + ni * 16 + l4 * 4;
      const float* bp = (col0 < bsp) ? b1 + col0 : b2 + (col0 - bsp);
      float4 bv = *(const float4*)bp;
      f32x4 a = acc[mi][ni];
      float v0 = (a[0] + bv.x) * sc;
      float v1 = (a[1] + bv.y) * sc;
      float v2 = (a[2] + bv.z) * sc;
      float v3 = (a[3] + bv.w) * sc;
      if (col0 >= asp) {
        v0 = v0 > 0.f ? v0 : (__expf(v0) - 1.f);
        v1 = v1 > 0.f ? v1 : (__expf(v1) - 1.f);
        v2 = v2 > 0.f ? v2 : (__expf(v2) - 1.f);
        v3 = v3 > 0.f ? v3 : (__expf(v3) - 1.f);
      }
      ushort4 st;
      st.x = f2bf(v0); st.y = f2bf(v1); st.z = f2bf(v2); st.w = f2bf(v3);
      u16* cp = (col0 < csp) ? C1b + (size_t)row * lc1 + col0
                             : C2b + (size_t)row * lc2 + (col0 - csp);
      *(ushort4*)cp = st;
    }
  }
}

// ---------- bf16 GEMM v3 (BM=64) for ao / agh ----------
template <int BM>
__global__ __launch_bounds__(256, 4) void gemm_v3(
    const u16* __restrict__ A, const u16* __restrict__ A2,
    const u16* __restrict__ Bw,
    u16* __restrict__ C1, u16* __restrict__ C2, int csplit, int ldc1, int ldc2,
    const float* __restrict__ bias1, const float* __restrict__ bias2, int bsplit,
    int K, int ksplit, int lda, int lda2, int ldb,
    long sAz, long sBz, long sC1z, long sC2z, int sb1z, int sb2z,
    float scale, int act_split, int nx) {
  constexpr int nA = BM / 16;
  constexpr int NFR = nA + 8;
  constexpr int FPW = NFR / 4;
  constexpr int MI = BM / 32;
  constexpr int SB = nA * 512;
  __shared__ __align__(16) u16 S[NFR * 512];
  const int wave = threadIdx.x >> 6, lane = threadIdx.x & 63;
  const int l15 = lane & 15, l4 = lane >> 4;

  const int flat = blockIdx.x;
  const int xcd = flat & 7;
  const unsigned s = flat >> 3;
  const int x = s % nx;
  const int yz = (s / nx) * 8 + xcd;
  constexpr int NY = 8192 / BM;
  const int y = yz & (NY - 1), z = yz / NY;
  const int tM = y * BM, tN = x * 128;

  A  += (size_t)z * sAz;
  A2 += (size_t)z * sAz;
  Bw += (size_t)z * sBz;
  const u16* p1[FPW];
  const u16* p2[FPW];
  u16* dst[FPW];
  int kspl[FPW];
  const int kch = l4 * 8;
#pragma unroll
  for (int t = 0; t < FPW; ++t) {
    const int fr = wave * FPW + t;
    if (fr < nA) {
      const int row = tM + fr * 16 + l15;
      p1[t] = A + (size_t)row * lda + kch;
      p2[t] = A2 + ((long)row * lda2 + kch - ksplit);
      dst[t] = &S[fr * 512];
      kspl[t] = ksplit;
    } else {
      const int g = fr - nA;
      const int row = tN + g * 16 + l15;
      p1[t] = Bw + (size_t)row * ldb + kch;
      p2[t] = p1[t];
      dst[t] = &S[SB + g * 512];
      kspl[t] = BIGI;
    }
  }

  const int wr = wave >> 1, wc = wave & 1;
  f32x4 acc[MI][4];
#pragma unroll
  for (int i = 0; i < MI; i++)
#pragma unroll
    for (int j = 0; j < 4; j++) acc[i][j] = (f32x4){0.f, 0.f, 0.f, 0.f};

  for (int k0 = 0; k0 < K; k0 += 32) {
    __syncthreads();
#pragma unroll
    for (int t = 0; t < FPW; ++t)
      gload16((k0 < kspl[t] ? p1[t] : p2[t]) + k0, dst[t]);
    __syncthreads();
    bf16x8 af[MI], bfr[4];
#pragma unroll
    for (int mi = 0; mi < MI; mi++)
      af[mi] = *(const bf16x8*)&S[(wr * MI + mi) * 512 + lane * 8];
#pragma unroll
    for (int ni = 0; ni < 4; ni++)
      bfr[ni] = *(const bf16x8*)&S[SB + (wc * 4 + ni) * 512 + lane * 8];
#pragma unroll
    for (int mi = 0; mi < MI; mi++)
#pragma unroll
      for (int ni = 0; ni < 4; ni++)
        acc[mi][ni] = __builtin_amdgcn_mfma_f32_16x16x32_bf16(bfr[ni], af[mi], acc[mi][ni], 0, 0, 0);
  }

#pragma unroll
  for (int mi = 0; mi < MI; mi++) {
    const int row = tM + wr * (BM / 2) + mi * 16 + l15;
#pragma unroll
    for (int ni = 0; ni < 4; ni++) {
      const int col0 = tN + wc * 64 + ni * 16 + l4 * 4;
      const float* bp = (col0 < bsplit) ? bias1 + (size_t)z * sb1z + col0
                                        : bias2 + (size_t)z * sb2z + (col0 - bsplit);
      float4 bv = *(const float4*)bp;
      f32x4 a = acc[mi][ni];
      float v0 = (a[0] + bv.x) * scale;
      float v1 = (a[1] + bv.y) * scale;
      float v2 = (a[2] + bv.z) * scale;
      float v3 = (a[3] + bv.w) * scale;
      if (col0 >= act_split) {
        v0 = v0 > 0.f ? v0 : (__expf(v0) - 1.f);
        v1 = v1 > 0.f ? v1 : (__expf(v1) - 1.f);
        v2 = v2 > 0.f ? v2 : (__expf(v2) - 1.f);
        v3 = v3 > 0.f ? v3 : (__expf(v3) - 1.f);
      }
      ushort4 st;
      st.x = f2bf(v0); st.y = f2bf(v1); st.z = f2bf(v2); st.w = f2bf(v3);
      u16* cp = (col0 < csplit)
                    ? C1 + (size_t)z * sC1z + (size_t)row * ldc1 + col0
                    : C2 + (size_t)z * sC2z + (size_t)row * ldc2 + (col0 - csplit);
      *(ushort4*)cp = st;
    }
  }
}

// ---------- attention ----------
__global__ __launch_bounds__(256) void attn_kernel(
    const u16* __restrict__ q, const u16* __restrict__ kv,
    u16* __restrict__ attn, float* __restrict__ influ) {
  const int wave = threadIdx.x >> 6, lane = threadIdx.x & 63;
  const int b = blockIdx.x * 4 + wave;
  const size_t qb = (size_t)b * 512;
  float wacc0 = 0.f, wacc1 = 0.f, wacc2 = 0.f;
#pragma unroll
  for (int h = 0; h < 4; ++h) {
    const int off = h * 128 + lane * 2;
    ushort2 qu = *(const ushort2*)(q + qb + off);
    float qx = bf2f(qu.x), qy = bf2f(qu.y);
    float s[3];
#pragma unroll
    for (int o = 0; o < 3; ++o) {
      ushort2 ku = *(const ushort2*)(kv + (size_t)o * (Bsz * 1024) + (size_t)b * 1024 + off);
      float p = qx * bf2f(ku.x) + qy * bf2f(ku.y);
#pragma unroll
      for (int d = 32; d; d >>= 1) p += __shfl_xor(p, d, 64);
      s[o] = p;
    }
    float m = fmaxf(s[0], fmaxf(s[1], s[2]));
    float e0 = __expf(s[0] - m), e1 = __expf(s[1] - m), e2 = __expf(s[2] - m);
    float inv = 1.f / (e0 + e1 + e2);
    float w0 = e0 * inv, w1 = e1 * inv, w2 = e2 * inv;
    wacc0 += w0; wacc1 += w1; wacc2 += w2;
    float ax = 0.f, ay = 0.f;
#pragma unroll
    for (int o = 0; o < 3; ++o) {
      float w = (o == 0) ? w0 : (o == 1) ? w1 : w2;
      ushort2 vu = *(const ushort2*)(kv + (size_t)o * (Bsz * 1024) + (size_t)b * 1024 + 512 + off);
      ax += w * bf2f(vu.x);
      ay += w * bf2f(vu.y);
    }
    ushort2 st; st.x = f2bf(ax); st.y = f2bf(ay);
    *(ushort2*)(attn + qb + off) = st;
  }
  if (lane == 0) {
    influ[b * 3 + 0] = wacc0 * 0.25f;
    influ[b * 3 + 1] = wacc1 * 0.25f;
    influ[b * 3 + 2] = wacc2 * 0.25f;
  }
}

// ---------- final heads ----------
__global__ __launch_bounds__(256) void heads_kernel(
    const u16* __restrict__ ah, const u16* __restrict__ oh,
    const float* __restrict__ Wap, const float* __restrict__ bap,
    const float* __restrict__ Wav, const float* __restrict__ bav,
    const float* __restrict__ Wop, const float* __restrict__ bop,
    const float* __restrict__ Wov, const float* __restrict__ bov,
    float* __restrict__ out) {
  __shared__ float sW[14336];
  for (int i = threadIdx.x; i < 14336; i += 256) {
    int s = i / 3584, rem = i - s * 3584;
    float v;
    if (s == 0) {
      v = (rem < 3072) ? Wap[rem] : Wav[rem - 3072];
    } else {
      int o = s - 1;
      v = (rem < 3072) ? Wop[o * 3072 + rem] : Wov[o * 512 + (rem - 3072)];
    }
    sW[i] = v;
  }
  __syncthreads();
  const int wave = threadIdx.x >> 6, lane = threadIdx.x & 63;
  const int kq = lane & 7, r = lane >> 3;
  const int b = blockIdx.x * 32 + wave * 8 + r;

  const u16* srcs[4] = {ah + (size_t)b * 512,
                        oh + (size_t)b * 512,
                        oh + (size_t)(Bsz + b) * 512,
                        oh + (size_t)(2 * Bsz + b) * 512};
  bf16x8 a[4][8];
#pragma unroll
  for (int s = 0; s < 4; s++)
#pragma unroll
    for (int c = 0; c < 8; c++)
      a[s][c] = *(const bf16x8*)(srcs[s] + c * 64 + kq * 8);

#pragma unroll
  for (int s = 0; s < 4; s++) {
#pragma unroll
    for (int p = 0; p < 7; p++) {
      const float* w = &sW[s * 3584 + p * 512 + kq * 8];
      float acc = 0.f;
#pragma unroll
      for (int c = 0; c < 8; c++) {
#pragma unroll
        for (int j = 0; j < 8; j++)
          acc += (float)a[s][c][j] * w[c * 64 + j];
      }
      acc += __shfl_xor(acc, 1, 64);
      acc += __shfl_xor(acc, 2, 64);
      acc += __shfl_xor(acc, 4, 64);
      if (kq == p) {
        if (s == 0) {
          if (p < 6) out[OUT_AP + b * 6 + p] = acc + bap[p];
          else       out[OUT_AV + b] = acc + bav[0];
        } else {
          int o = s - 1;
          if (p < 6) out[OUT_OP + b * 18 + o * 6 + p] = acc + bop[o * 6 + p];
          else       out[OUT_OV + b * 3 + o] = acc + bov[o];
        }
      }
    }
  }
}

extern "C" void kernel_launch(void* const* d_in, const int* in_sizes, int n_in,
                              void* d_out, int out_size, void* d_ws, size_t ws_size,
                              hipStream_t stream) {
  (void)in_sizes; (void)n_in; (void)out_size; (void)ws_size;
  const float* f     = (const float*)d_in[0];
  const float* W_al  = (const float*)d_in[1];
  const float* b_al  = (const float*)d_in[2];
  const float* W_in  = (const float*)d_in[3];
  const float* b_in  = (const float*)d_in[4];
  const float* W_out = (const float*)d_in[5];
  const float* b_out = (const float*)d_in[6];
  const float* W_ah  = (const float*)d_in[7];
  const float* b_ah  = (const float*)d_in[8];
  const float* W_ap  = (const float*)d_in[9];
  const float* b_ap  = (const float*)d_in[10];
  const float* W_av  = (const float*)d_in[11];
  const float* b_av  = (const float*)d_in[12];
  const float* W_ol  = (const float*)d_in[13];
  const float* b_ol  = (const float*)d_in[14];
  const float* W_oh  = (const float*)d_in[15];
  const float* b_oh  = (const float*)d_in[16];
  const float* W_op  = (const float*)d_in[17];
  const float* b_op  = (const float*)d_in[18];
  const float* W_ov  = (const float*)d_in[19];
  const float* b_ov  = (const float*)d_in[20];
  float* out = (float*)d_out;
  u16* ws = (u16*)d_ws;

  u16* feat  = ws + OFF_FEAT;
  u16* wcomb = ws + OFF_WCOMB;
  u16* wq    = ws + OFF_WQ;
  u16* wout  = ws + OFF_WOUT;
  u16* wah   = ws + OFF_WAH;
  u16* pack  = ws + OFF_PACK;
  u16* lat   = ws + OFF_LAT;
  u16* qb    = ws + OFF_Q;
  u16* kvb   = ws + OFF_KV;
  u16* att   = ws + OFF_ATT;
  u16* ao    = ws + OFF_AO;
  u16* agh   = ws + OFF_Q;   // reuse q's slot after attention
  u16* oph   = ws + OFF_OPH;

  convert_all<<<13568, 256, 0, stream>>>(f, W_al, W_ol, W_in, W_out, W_ah, W_oh, ws);

  // lat = elu(feat @ [W_al;W_ol]^T + [b_al;b_ol])  (B x 2048)
  gemm_v6<<<1024, 256, 0, stream>>>(
      feat, wcomb, lat, lat, BIGI, 2048, 2048,
      b_al, b_ol, 512, 1024, 1024, 1024,
      0, 0, 0, 0, 0, 1.f, 0, 16,
      0, feat, wcomb, lat, b_al, 1.f);

  // fused: q (blocks 0..255) + merged kv/oph (blocks 256..2559)
  // q:   qb = (agent_latent @ Wq^T + bq) / sqrt(128)
  // kv:  kvb[z] cols 0..1023 (no act); oph[z] cols 1024..1535 (ELU)
  gemm_v6<<<2560, 256, 0, stream>>>(
      lat + 512, pack, kvb, oph, 1024, 1024, 512,
      b_in + 512, b_oh, 1024, 512, 2048, 512,
      512, 786432, 8388608, 4194304, 512, 1.f, 1024, 12,
      256, lat, wq, qb, b_in, 0.08838834764831845f);

  attn_kernel<<<2048, 256, 0, stream>>>(qb, kvb, att, out + OUT_IN);

  // attn_out = attn @ W_out^T + b_out
  gemm_v3<64><<<512, 256, 0, stream>>>(
      att, att, wout, ao, ao, BIGI, 512, 512,
      b_out, b_out, BIGI, 512, BIGI, 512, 512, 512,
      0, 0, 0, 0, 0, 0, 1.f, BIGI, 4);
  // agent_head = elu([agent_latent | attn_out] @ W_ah^T + b_ah)  (split-A)
  gemm_v3<64><<<512, 256, 0, stream>>>(
      lat, ao, wah, agh, agh, BIGI, 512, 512,
      b_ah, b_ah, BIGI, 1024, 512, 2048, 512, 1024,
      0, 0, 0, 0, 0, 0, 1.f, 0, 4);

  heads_kernel<<<256, 256, 0, stream>>>(agh, oph, W_ap, b_ap, W_av, b_av,
                                        W_op, b_op, W_ov, b_ov, out);
}